// Round 9
// baseline (457.366 us; speedup 1.0000x reference)
//
#include <hip/hip_runtime.h>
#include <cfloat>

#define TT 16
#define KK 512
#define DD 128
#define BSTRIPE 512   // b rows per block -> grid 16x16 = 256 blocks = 1/CU
#define BC 32         // b rows per chunk
#define NW 16         // waves per block (1024 threads, 4 waves/SIMD)
#define NCHUNK (BSTRIPE / BC)
#define N0 16777216   // 8192*16*128 (z_q_st)
#define N1 131072     // 8192*16     (tokens)
#define TAU 1e-4f     // rescore margin (~6 ulp at dist~128, >>1e-7 mfma-path err)

typedef _Float16 half8 __attribute__((ext_vector_type(8)));
typedef float f32x16 __attribute__((ext_vector_type(16)));

// numpy pairwise-sum (n<=128: 8 strided accumulators + tree combine) of x^2
// UNCHANGED from passing kernel: must match reference ||.||^2 rounding.
__device__ __forceinline__ float np_sum128_sq_f4(const float4* __restrict__ p) {
  float4 a = p[0], b = p[1];
  float r[8];
  r[0] = __fmul_rn(a.x, a.x); r[1] = __fmul_rn(a.y, a.y);
  r[2] = __fmul_rn(a.z, a.z); r[3] = __fmul_rn(a.w, a.w);
  r[4] = __fmul_rn(b.x, b.x); r[5] = __fmul_rn(b.y, b.y);
  r[6] = __fmul_rn(b.z, b.z); r[7] = __fmul_rn(b.w, b.w);
#pragma unroll
  for (int i = 1; i < 16; ++i) {
    a = p[2 * i]; b = p[2 * i + 1];
    r[0] = __fadd_rn(r[0], __fmul_rn(a.x, a.x));
    r[1] = __fadd_rn(r[1], __fmul_rn(a.y, a.y));
    r[2] = __fadd_rn(r[2], __fmul_rn(a.z, a.z));
    r[3] = __fadd_rn(r[3], __fmul_rn(a.w, a.w));
    r[4] = __fadd_rn(r[4], __fmul_rn(b.x, b.x));
    r[5] = __fadd_rn(r[5], __fmul_rn(b.y, b.y));
    r[6] = __fadd_rn(r[6], __fmul_rn(b.z, b.z));
    r[7] = __fadd_rn(r[7], __fmul_rn(b.w, b.w));
  }
  return __fadd_rn(__fadd_rn(__fadd_rn(r[0], r[1]), __fadd_rn(r[2], r[3])),
                   __fadd_rn(__fadd_rn(r[4], r[5]), __fadd_rn(r[6], r[7])));
}

// bit-exact replica of the ORIGINAL passing kernel's dot accumulation:
// single fma chain over d=0..127 in order, 4 elems per float4.
__device__ __forceinline__ float dot128_chain(const float* __restrict__ zp,
                                              const float* __restrict__ cp) {
  float s = 0.0f;
#pragma unroll
  for (int d4 = 0; d4 < 32; ++d4) {
    const float4 a = *(const float4*)(zp + d4 * 4);
    const float4 c = *(const float4*)(cp + d4 * 4);
    s = __builtin_fmaf(a.x, c.x, s);
    s = __builtin_fmaf(a.y, c.y, s);
    s = __builtin_fmaf(a.z, c.z, s);
    s = __builtin_fmaf(a.w, c.w, s);
  }
  return s;
}

// split 8 fp32 (pre-scaled by exact pow2) into two f16 halves: v*sc = p1 + p2 + O(2^-22 v)
__device__ __forceinline__ void split8(const float4 a, const float4 b, const float sc,
                                       half8& h1, half8& h2) {
  const float v[8] = {a.x, a.y, a.z, a.w, b.x, b.y, b.z, b.w};
#pragma unroll
  for (int i = 0; i < 8; ++i) {
    const float s = __fmul_rn(v[i], sc);   // exact (pow2 scale)
    const _Float16 p = (_Float16)s;
    const float rr = __fsub_rn(s, (float)p);  // exact (Sterbenz)
    h1[i] = p;
    h2[i] = (_Float16)rr;
  }
}

// split1 only (same rounding as split8's h1)
__device__ __forceinline__ half8 split8_hi(const float4 a, const float4 b, const float sc) {
  const float v[8] = {a.x, a.y, a.z, a.w, b.x, b.y, b.z, b.w};
  half8 h;
#pragma unroll
  for (int i = 0; i < 8; ++i) h[i] = (_Float16)__fmul_rn(v[i], sc);
  return h;
}

__global__ void __launch_bounds__(1024, 1)
vq_main(const float* __restrict__ z_e, const float* __restrict__ cb,
        float* __restrict__ out, float* __restrict__ loss_part,
        int* __restrict__ used) {
  // cb split2 for ALL 512 k rows: [k][16 slots of 16B], slot ^= (k&15). 128 KB.
  __shared__ alignas(16) _Float16 cb2s[KK * DD];
  // z-chunk f16 splits [32 rows][2 splits * 128 d], 16B-chunk XOR swizzle on row
  __shared__ alignas(16) _Float16 zs[BC * 256];
  __shared__ float qs[KK];
  __shared__ float As_all[BSTRIPE];
  __shared__ int tok_all[BSTRIPE];
  __shared__ unsigned long long mrg[BC * (2 * NW)];
  __shared__ float wred[NW];

  const int tid = threadIdx.x;
  const int t = blockIdx.y;
  const int bbase = blockIdx.x * BSTRIPE;
  const int w = tid >> 6;         // wave 0..15; owns k-rows [w*32, w*32+32)
  const int lane = tid & 63;
  const int lr = lane & 31;       // M-row / N-col within tile
  const int lhi = lane >> 5;      // k-half select

  // ---- block init (split across the 1024 threads) ----
  if (tid < KK) {
    // stream cb row k=tid: qs (np pairwise order) + split2 -> LDS
    const int k = tid;
    const float* src = cb + ((size_t)t * KK + k) * DD;
    float r[8];
    half8 p1, p2;
    {
      const float4 a = *(const float4*)(src);
      const float4 b = *(const float4*)(src + 4);
      r[0] = __fmul_rn(a.x, a.x); r[1] = __fmul_rn(a.y, a.y);
      r[2] = __fmul_rn(a.z, a.z); r[3] = __fmul_rn(a.w, a.w);
      r[4] = __fmul_rn(b.x, b.x); r[5] = __fmul_rn(b.y, b.y);
      r[6] = __fmul_rn(b.z, b.z); r[7] = __fmul_rn(b.w, b.w);
      split8(a, b, 8192.0f, p1, p2);
      *(half8*)(cb2s + k * DD + ((0 ^ (k & 15)) * 8)) = p2;
    }
#pragma unroll
    for (int g = 1; g < 16; ++g) {
      const float4 a = *(const float4*)(src + g * 8);
      const float4 b = *(const float4*)(src + g * 8 + 4);
      r[0] = __fadd_rn(r[0], __fmul_rn(a.x, a.x));
      r[1] = __fadd_rn(r[1], __fmul_rn(a.y, a.y));
      r[2] = __fadd_rn(r[2], __fmul_rn(a.z, a.z));
      r[3] = __fadd_rn(r[3], __fmul_rn(a.w, a.w));
      r[4] = __fadd_rn(r[4], __fmul_rn(b.x, b.x));
      r[5] = __fadd_rn(r[5], __fmul_rn(b.y, b.y));
      r[6] = __fadd_rn(r[6], __fmul_rn(b.z, b.z));
      r[7] = __fadd_rn(r[7], __fmul_rn(b.w, b.w));
      split8(a, b, 8192.0f, p1, p2);
      *(half8*)(cb2s + k * DD + ((g ^ (k & 15)) * 8)) = p2;
    }
    qs[k] = __fadd_rn(__fadd_rn(__fadd_rn(r[0], r[1]), __fadd_rn(r[2], r[3])),
                      __fadd_rn(__fadd_rn(r[4], r[5]), __fadd_rn(r[6], r[7])));
  } else {
    // ||z||^2 for all 512 stripe rows (np pairwise order)
    const int row = tid - KK;
    As_all[row] = np_sum128_sq_f4(
        (const float4*)(z_e + ((size_t)(bbase + row) * TT + t) * DD));
  }

  // cb split1 -> registers (32 VGPR). Wave owns k-rows [w*32, w*32+32).
  half8 ca[8];  // [dstep]
  {
    const int krow = w * 32 + lr;
    const float* src = cb + ((size_t)t * KK + krow) * DD + 8 * lhi;
#pragma unroll
    for (int ds = 0; ds < 8; ++ds) {
      const float4 a = *(const float4*)(src + ds * 16);
      const float4 b = *(const float4*)(src + ds * 16 + 4);
      ca[ds] = split8_hi(a, b, 8192.0f);  // c'' = c * 2^13
    }
  }

  float lsum = 0.0f;
  const int srow = tid >> 4, sunit = tid & 15;  // staging coords (tid<512)

  // prefetch z chunk 0 into regs (32 B/thread, lower 512 threads)
  float4 pza, pzb;
  if (tid < 512) {
    const float* zp = z_e + ((size_t)(bbase + srow) * TT + t) * DD + sunit * 8;
    pza = *(const float4*)zp;
    pzb = *(const float4*)(zp + 4);
  }

#pragma unroll 1
  for (int bc = 0; bc < NCHUNK; ++bc) {
    const int b0 = bbase + bc * BC;
    __syncthreads();  // init visible (bc=0); mrg merged; zs free

    // ---- stage z chunk from prefetched regs -> f16 splits in LDS (swizzled) ----
    if (tid < 512) {
      half8 p1, p2;
      split8(pza, pzb, 128.0f, p1, p2);  // z'' = z * 2^7
      const int c1 = sunit ^ srow;       // 32-slot XOR over 512B row
      const int c2 = (16 + sunit) ^ srow;
      *(half8*)(zs + srow * 256 + c1 * 8) = p1;
      *(half8*)(zs + srow * 256 + c2 * 8) = p2;
    }
    __syncthreads();

    // issue next chunk's z prefetch (hidden under MFMA phase)
    if (tid < 512 && bc + 1 < NCHUNK) {
      const float* zp =
          z_e + ((size_t)(b0 + BC + srow) * TT + t) * DD + sunit * 8;
      pza = *(const float4*)zp;
      pzb = *(const float4*)(zp + 4);
    }

    // ---- 3-pass f16-split MFMA, one 32x32 mtile per wave ----
    f32x16 acc;
#pragma unroll
    for (int i = 0; i < 16; ++i) acc[i] = 0.0f;

    // pass 1: A1 (regs) x B1
#pragma unroll
    for (int ds = 0; ds < 8; ++ds) {
      const int ch = (ds * 2 + lhi) ^ lr;
      const half8 bf = *(const half8*)(zs + lr * 256 + ch * 8);
      acc = __builtin_amdgcn_mfma_f32_32x32x16_f16(ca[ds], bf, acc, 0, 0, 0);
    }
    // pass 2: A2 (cb split2 from LDS) x B1
#pragma unroll
    for (int ds = 0; ds < 8; ++ds) {
      const int g = ds * 2 + lhi;
      const int ch = g ^ lr;
      const half8 bf = *(const half8*)(zs + lr * 256 + ch * 8);
      const half8 a2 = *(const half8*)(cb2s + (size_t)(w * 32 + lr) * DD +
                                       ((g ^ (lr & 15)) * 8));
      acc = __builtin_amdgcn_mfma_f32_32x32x16_f16(a2, bf, acc, 0, 0, 0);
    }
    // pass 3: A1 x B2 (z split2 from LDS)
#pragma unroll
    for (int ds = 0; ds < 8; ++ds) {
      const int ch = (16 + ds * 2 + lhi) ^ lr;
      const half8 bf2 = *(const half8*)(zs + lr * 256 + ch * 8);
      acc = __builtin_amdgcn_mfma_f32_32x32x16_f16(ca[ds], bf2, acc, 0, 0, 0);
    }

    // ---- dist + packed best/second-best (u64 min => first-index ties) ----
    const float Ab = As_all[bc * BC + lr];
    unsigned long long b1 = ~0ULL, b2 = ~0ULL;
#pragma unroll
    for (int r = 0; r < 16; ++r) {
      const int k = w * 32 + (r & 3) + 8 * (r >> 2) + 4 * lhi;
      // 2*(z.c) = acc * 2^-19 exactly; same rounding structure as fp32 kernel
      const float dist =
          __fadd_rn(__fsub_rn(Ab, __fmul_rn(acc[r], 0x1p-19f)), qs[k]);
      const unsigned long long cand =
          ((unsigned long long)__float_as_uint(dist) << 32) | (unsigned)k;
      if (cand < b1) { b2 = b1; b1 = cand; }
      else if (cand < b2) { b2 = cand; }
    }
    {
      const unsigned long long o1 = __shfl_xor(b1, 32, 64);
      const unsigned long long o2 = __shfl_xor(b2, 32, 64);
      const unsigned long long lo = (b1 < o1) ? b1 : o1;
      const unsigned long long hi = (b1 < o1) ? o1 : b1;
      const unsigned long long s2 = (b2 < o2) ? b2 : o2;
      b1 = lo;
      b2 = (hi < s2) ? hi : s2;
    }
    if (lane < 32) {
      // slot XOR spreads banks; merge scans the whole row so order is free
      const int sl = (w * 2) ^ ((lr & 15) << 1);
      mrg[lr * (2 * NW) + sl] = b1;
      mrg[lr * (2 * NW) + sl + 1] = b2;
    }
    __syncthreads();

    // ---- merge + (rare) exact rescore: one thread per row, spread over waves ----
    if ((tid & 31) == 0) {
      const int row = tid >> 5;  // 0..31
      unsigned long long m1 = ~0ULL, m2 = ~0ULL;
#pragma unroll
      for (int g = 0; g < 2 * NW; ++g) {
        const unsigned long long v = mrg[row * (2 * NW) + g];
        if (v < m1) { m2 = m1; m1 = v; }
        else if (v < m2) { m2 = v; }
      }
      int tok = (int)(m1 & 0xffffffffULL);
      const float d1f = __uint_as_float((unsigned)(m1 >> 32));
      const float d2f = __uint_as_float((unsigned)(m2 >> 32));
      if (d2f - d1f < TAU) {
        // near-tie: rescore both candidates with the original kernel's exact
        // fp32 fma-chain (bit-identical decisions to the passing fp32 kernel)
        const int k1 = (int)(m1 & 0xffffffffULL);
        const int k2 = (int)(m2 & 0xffffffffULL);
        const float* zp = z_e + ((size_t)(b0 + row) * TT + t) * DD;
        const float Az = As_all[bc * BC + row];
        const float e1 = dot128_chain(zp, cb + ((size_t)t * KK + k1) * DD);
        const float e2 = dot128_chain(zp, cb + ((size_t)t * KK + k2) * DD);
        const float dd1 = __fadd_rn(__fsub_rn(Az, __fmul_rn(2.0f, e1)), qs[k1]);
        const float dd2 = __fadd_rn(__fsub_rn(Az, __fmul_rn(2.0f, e2)), qs[k2]);
        const unsigned long long c1 =
            ((unsigned long long)__float_as_uint(dd1) << 32) | (unsigned)k1;
        const unsigned long long c2 =
            ((unsigned long long)__float_as_uint(dd2) << 32) | (unsigned)k2;
        tok = (int)(((c1 < c2) ? c1 : c2) & 0xffffffffULL);
      }
      tok_all[bc * BC + row] = tok;
      out[(size_t)N0 + (size_t)(b0 + row) * TT + t] = (float)tok;
      atomicOr(&used[t * KK + tok], 1);
    }
    // loop-top sync covers mrg/zs reuse
  }
  __syncthreads();  // tok_all complete

  // ---- deferred epilogue: z_q_st = z + (c - z), loss partial (fully pipelined) ----
#pragma unroll
  for (int it = 0; it < 8; ++it) {
    const int idx = tid + it * 1024;
    const int row = idx >> 4, unit = idx & 15;
    const int k = tok_all[row];
    const float* zp = z_e + ((size_t)(bbase + row) * TT + t) * DD + unit * 8;
    const float* cp = cb + ((size_t)t * KK + k) * DD + unit * 8;
    float* op = out + ((size_t)(bbase + row) * TT + t) * DD + unit * 8;
#pragma unroll
    for (int h = 0; h < 2; ++h) {
      const float4 zv = *(const float4*)(zp + h * 4);
      const float4 cv = *(const float4*)(cp + h * 4);
      float4 o;
      o.x = __fadd_rn(zv.x, __fsub_rn(cv.x, zv.x));
      o.y = __fadd_rn(zv.y, __fsub_rn(cv.y, zv.y));
      o.z = __fadd_rn(zv.z, __fsub_rn(cv.z, zv.z));
      o.w = __fadd_rn(zv.w, __fsub_rn(cv.w, zv.w));
      *(float4*)(op + h * 4) = o;
      const float dx = zv.x - cv.x, dy = zv.y - cv.y;
      const float dz = zv.z - cv.z, dw = zv.w - cv.w;
      lsum += dx * dx + dy * dy + dz * dz + dw * dw;
    }
  }

  // ---- block loss reduction ----
#pragma unroll
  for (int off = 32; off > 0; off >>= 1) lsum += __shfl_down(lsum, off, 64);
  if (lane == 0) wred[w] = lsum;
  __syncthreads();
  if (tid == 0) {
    float s = 0.0f;
#pragma unroll
    for (int i = 0; i < NW; ++i) s += wred[i];
    loss_part[blockIdx.y * 16 + blockIdx.x] = s;
  }
}

__global__ void vq_final(const float* __restrict__ loss_part,
                         const int* __restrict__ used, float* __restrict__ out) {
  __shared__ float partf[4];
  __shared__ int   parti[4];
  int tid = threadIdx.x;
  float ls = 0.0f;
  for (int i = tid; i < 256; i += 256) ls += loss_part[i];
  int c = 0;
  for (int i = tid; i < TT * KK; i += 256) c += used[i];
#pragma unroll
  for (int off = 32; off > 0; off >>= 1) {
    ls += __shfl_down(ls, off, 64);
    c  += __shfl_down(c, off, 64);
  }
  if ((tid & 63) == 0) { partf[tid >> 6] = ls; parti[tid >> 6] = c; }
  __syncthreads();
  if (tid == 0) {
    float lt = partf[0] + partf[1] + partf[2] + partf[3];
    int   tot = parti[0] + parti[1] + parti[2] + parti[3];
    out[(size_t)N0 + N1]     = 0.25f * lt / 16777216.0f;  // BETA * mean
    out[(size_t)N0 + N1 + 1] = (float)tot / 8192.0f;      // utilization
  }
}

extern "C" void kernel_launch(void* const* d_in, const int* in_sizes, int n_in,
                              void* d_out, int out_size, void* d_ws, size_t ws_size,
                              hipStream_t stream) {
  const float* z_e = (const float*)d_in[0];
  const float* cb  = (const float*)d_in[1];
  float* out = (float*)d_out;
  float* loss_part = (float*)d_ws;                     // 256 floats
  int*   used      = (int*)((char*)d_ws + 4096);       // 8192 ints
  hipMemsetAsync(d_ws, 0, 4096 + TT * KK * sizeof(int), stream);
  vq_main<<<dim3(8192 / BSTRIPE, TT), 1024, 0, stream>>>(z_e, cb, out, loss_part, used);
  vq_final<<<1, 256, 0, stream>>>(loss_part, used, out);
}

// Round 10
// 281.280 us; speedup vs baseline: 1.6260x; 1.6260x over previous
//
#include <hip/hip_runtime.h>
#include <cfloat>

#define TT 16
#define KK 512
#define DD 128
#define BSTRIPE 512   // b rows per block -> grid 16x16 = 256 blocks = 1/CU
#define BC 32         // b rows per chunk
#define NW 8          // waves per block (512 threads; compiler's 128-VGPR regime)
#define NCHUNK (BSTRIPE / BC)
#define N0 16777216   // 8192*16*128 (z_q_st)
#define N1 131072     // 8192*16     (tokens)
#define TAU 1e-4f     // rescore margin (~6 ulp at dist~128, >>1e-7 mfma-path err)

typedef _Float16 half8 __attribute__((ext_vector_type(8)));
typedef float f32x16 __attribute__((ext_vector_type(16)));

// numpy pairwise-sum (n<=128: 8 strided accumulators + tree combine) of x^2
// UNCHANGED from passing kernel: must match reference ||.||^2 rounding.
__device__ __forceinline__ float np_sum128_sq_f4(const float4* __restrict__ p) {
  float4 a = p[0], b = p[1];
  float r[8];
  r[0] = __fmul_rn(a.x, a.x); r[1] = __fmul_rn(a.y, a.y);
  r[2] = __fmul_rn(a.z, a.z); r[3] = __fmul_rn(a.w, a.w);
  r[4] = __fmul_rn(b.x, b.x); r[5] = __fmul_rn(b.y, b.y);
  r[6] = __fmul_rn(b.z, b.z); r[7] = __fmul_rn(b.w, b.w);
#pragma unroll
  for (int i = 1; i < 16; ++i) {
    a = p[2 * i]; b = p[2 * i + 1];
    r[0] = __fadd_rn(r[0], __fmul_rn(a.x, a.x));
    r[1] = __fadd_rn(r[1], __fmul_rn(a.y, a.y));
    r[2] = __fadd_rn(r[2], __fmul_rn(a.z, a.z));
    r[3] = __fadd_rn(r[3], __fmul_rn(a.w, a.w));
    r[4] = __fadd_rn(r[4], __fmul_rn(b.x, b.x));
    r[5] = __fadd_rn(r[5], __fmul_rn(b.y, b.y));
    r[6] = __fadd_rn(r[6], __fmul_rn(b.z, b.z));
    r[7] = __fadd_rn(r[7], __fmul_rn(b.w, b.w));
  }
  return __fadd_rn(__fadd_rn(__fadd_rn(r[0], r[1]), __fadd_rn(r[2], r[3])),
                   __fadd_rn(__fadd_rn(r[4], r[5]), __fadd_rn(r[6], r[7])));
}

// bit-exact replica of the ORIGINAL passing kernel's dot accumulation:
// single fma chain over d=0..127 in order, 4 elems per float4.
__device__ __forceinline__ float dot128_chain(const float* __restrict__ zp,
                                              const float* __restrict__ cp) {
  float s = 0.0f;
#pragma unroll
  for (int d4 = 0; d4 < 32; ++d4) {
    const float4 a = *(const float4*)(zp + d4 * 4);
    const float4 c = *(const float4*)(cp + d4 * 4);
    s = __builtin_fmaf(a.x, c.x, s);
    s = __builtin_fmaf(a.y, c.y, s);
    s = __builtin_fmaf(a.z, c.z, s);
    s = __builtin_fmaf(a.w, c.w, s);
  }
  return s;
}

// split 8 fp32 (pre-scaled by exact pow2) into two f16 halves: v*sc = p1 + p2 + O(2^-22 v)
__device__ __forceinline__ void split8(const float4 a, const float4 b, const float sc,
                                       half8& h1, half8& h2) {
  const float v[8] = {a.x, a.y, a.z, a.w, b.x, b.y, b.z, b.w};
#pragma unroll
  for (int i = 0; i < 8; ++i) {
    const float s = __fmul_rn(v[i], sc);   // exact (pow2 scale)
    const _Float16 p = (_Float16)s;
    const float rr = __fsub_rn(s, (float)p);  // exact (Sterbenz)
    h1[i] = p;
    h2[i] = (_Float16)rr;
  }
}

// split1 only (same rounding as split8's h1)
__device__ __forceinline__ half8 split8_hi(const float4 a, const float4 b, const float sc) {
  const float v[8] = {a.x, a.y, a.z, a.w, b.x, b.y, b.z, b.w};
  half8 h;
#pragma unroll
  for (int i = 0; i < 8; ++i) h[i] = (_Float16)__fmul_rn(v[i], sc);
  return h;
}

__global__ void __launch_bounds__(512, 1)
vq_main(const float* __restrict__ z_e, const float* __restrict__ cb,
        float* __restrict__ out, float* __restrict__ loss_part,
        int* __restrict__ used) {
  // cb split2 for ALL 512 k rows: [k][16 slots of 16B], slot ^= (k&15). 128 KB.
  __shared__ alignas(16) _Float16 cb2s[KK * DD];
  // z-chunk f16 splits [32 rows][2 splits * 128 d], 16B-chunk XOR swizzle on row
  __shared__ alignas(16) _Float16 zs[BC * 256];
  __shared__ float qs[KK];
  __shared__ float As_all[BSTRIPE];
  __shared__ int tok_all[BSTRIPE];
  __shared__ unsigned long long mrg[(2 * NW) * BC];  // [slot][row] transposed
  __shared__ float wred[NW];

  const int tid = threadIdx.x;
  const int t = blockIdx.y;
  const int bbase = blockIdx.x * BSTRIPE;
  const int w = tid >> 6;         // wave 0..7; owns k-rows [w*64, w*64+64)
  const int lane = tid & 63;
  const int lr = lane & 31;       // M-row / N-col within tile
  const int lhi = lane >> 5;      // k-half select

  // ---- block init: cb row k=tid (qs + split2->LDS) AND z row tid (As_all) ----
  {
    const int k = tid;
    const float* src = cb + ((size_t)t * KK + k) * DD;
    float r[8];
    half8 p1, p2;
    {
      const float4 a = *(const float4*)(src);
      const float4 b = *(const float4*)(src + 4);
      r[0] = __fmul_rn(a.x, a.x); r[1] = __fmul_rn(a.y, a.y);
      r[2] = __fmul_rn(a.z, a.z); r[3] = __fmul_rn(a.w, a.w);
      r[4] = __fmul_rn(b.x, b.x); r[5] = __fmul_rn(b.y, b.y);
      r[6] = __fmul_rn(b.z, b.z); r[7] = __fmul_rn(b.w, b.w);
      split8(a, b, 8192.0f, p1, p2);
      *(half8*)(cb2s + k * DD + ((0 ^ (k & 15)) * 8)) = p2;
    }
#pragma unroll
    for (int g = 1; g < 16; ++g) {
      const float4 a = *(const float4*)(src + g * 8);
      const float4 b = *(const float4*)(src + g * 8 + 4);
      r[0] = __fadd_rn(r[0], __fmul_rn(a.x, a.x));
      r[1] = __fadd_rn(r[1], __fmul_rn(a.y, a.y));
      r[2] = __fadd_rn(r[2], __fmul_rn(a.z, a.z));
      r[3] = __fadd_rn(r[3], __fmul_rn(a.w, a.w));
      r[4] = __fadd_rn(r[4], __fmul_rn(b.x, b.x));
      r[5] = __fadd_rn(r[5], __fmul_rn(b.y, b.y));
      r[6] = __fadd_rn(r[6], __fmul_rn(b.z, b.z));
      r[7] = __fadd_rn(r[7], __fmul_rn(b.w, b.w));
      split8(a, b, 8192.0f, p1, p2);
      *(half8*)(cb2s + k * DD + ((g ^ (k & 15)) * 8)) = p2;
    }
    qs[k] = __fadd_rn(__fadd_rn(__fadd_rn(r[0], r[1]), __fadd_rn(r[2], r[3])),
                      __fadd_rn(__fadd_rn(r[4], r[5]), __fadd_rn(r[6], r[7])));
    // ||z||^2 for stripe row tid (np pairwise order)
    As_all[tid] = np_sum128_sq_f4(
        (const float4*)(z_e + ((size_t)(bbase + tid) * TT + t) * DD));
  }

  // cb split1 -> registers (64 VGPR). Wave owns k-rows [w*64, w*64+64).
  half8 ca[2][8];  // [mtile][dstep]
#pragma unroll
  for (int mt = 0; mt < 2; ++mt) {
    const int krow = w * 64 + mt * 32 + lr;
    const float* src = cb + ((size_t)t * KK + krow) * DD + 8 * lhi;
#pragma unroll
    for (int ds = 0; ds < 8; ++ds) {
      const float4 a = *(const float4*)(src + ds * 16);
      const float4 b = *(const float4*)(src + ds * 16 + 4);
      ca[mt][ds] = split8_hi(a, b, 8192.0f);  // c'' = c * 2^13
    }
  }

  const int srow = tid >> 4, sunit = tid & 15;  // staging coords

  // prefetch z chunk 0 into regs (32 B/thread)
  float4 pza, pzb;
  {
    const float* zp = z_e + ((size_t)(bbase + srow) * TT + t) * DD + sunit * 8;
    pza = *(const float4*)zp;
    pzb = *(const float4*)(zp + 4);
  }
  __syncthreads();  // init (cb2s/qs/As_all) visible

#pragma unroll 1
  for (int bc = 0; bc < NCHUNK; ++bc) {
    const int b0 = bbase + bc * BC;

    // ---- stage z chunk from prefetched regs -> f16 splits in LDS (swizzled) ----
    {
      half8 p1, p2;
      split8(pza, pzb, 128.0f, p1, p2);  // z'' = z * 2^7
      const int c1 = sunit ^ srow;       // 32-slot XOR over 512B row
      const int c2 = (16 + sunit) ^ srow;
      *(half8*)(zs + srow * 256 + c1 * 8) = p1;
      *(half8*)(zs + srow * 256 + c2 * 8) = p2;
    }
    __syncthreads();  // B1: zs staged

    // issue next chunk's z prefetch (lands during MFMA phase)
    if (bc + 1 < NCHUNK) {
      const float* zp =
          z_e + ((size_t)(b0 + BC + srow) * TT + t) * DD + sunit * 8;
      pza = *(const float4*)zp;
      pzb = *(const float4*)(zp + 4);
    }

    // ---- 3-pass f16-split MFMA: acc = sum_d z''*c'' (= 2^20 * z.c) ----
    f32x16 acc0, acc1;
#pragma unroll
    for (int i = 0; i < 16; ++i) { acc0[i] = 0.0f; acc1[i] = 0.0f; }

    // pass 1: A1 (regs) x B1
#pragma unroll
    for (int ds = 0; ds < 8; ++ds) {
      const int ch = (ds * 2 + lhi) ^ lr;
      const half8 bf = *(const half8*)(zs + lr * 256 + ch * 8);
      acc0 = __builtin_amdgcn_mfma_f32_32x32x16_f16(ca[0][ds], bf, acc0, 0, 0, 0);
      acc1 = __builtin_amdgcn_mfma_f32_32x32x16_f16(ca[1][ds], bf, acc1, 0, 0, 0);
    }
    // pass 2: A2 (cb split2 from LDS) x B1
#pragma unroll
    for (int ds = 0; ds < 8; ++ds) {
      const int g = ds * 2 + lhi;
      const int ch = g ^ lr;
      const half8 bf = *(const half8*)(zs + lr * 256 + ch * 8);
      const half8 a2_0 =
          *(const half8*)(cb2s + (size_t)(w * 64 + lr) * DD + ((g ^ (lr & 15)) * 8));
      const half8 a2_1 =
          *(const half8*)(cb2s + (size_t)(w * 64 + 32 + lr) * DD + ((g ^ (lr & 15)) * 8));
      acc0 = __builtin_amdgcn_mfma_f32_32x32x16_f16(a2_0, bf, acc0, 0, 0, 0);
      acc1 = __builtin_amdgcn_mfma_f32_32x32x16_f16(a2_1, bf, acc1, 0, 0, 0);
    }
    // pass 3: A1 x B2 (z split2 from LDS)
#pragma unroll
    for (int ds = 0; ds < 8; ++ds) {
      const int ch = (16 + ds * 2 + lhi) ^ lr;
      const half8 bf2 = *(const half8*)(zs + lr * 256 + ch * 8);
      acc0 = __builtin_amdgcn_mfma_f32_32x32x16_f16(ca[0][ds], bf2, acc0, 0, 0, 0);
      acc1 = __builtin_amdgcn_mfma_f32_32x32x16_f16(ca[1][ds], bf2, acc1, 0, 0, 0);
    }

    // ---- dist + packed best/second-best (u64 min => first-index ties) ----
    const float Ab = As_all[bc * BC + lr];
    unsigned long long b1 = ~0ULL, b2 = ~0ULL;
#pragma unroll
    for (int mt = 0; mt < 2; ++mt) {
#pragma unroll
      for (int r = 0; r < 16; ++r) {
        const int k = w * 64 + mt * 32 + (r & 3) + 8 * (r >> 2) + 4 * lhi;
        const float av = (mt == 0) ? acc0[r] : acc1[r];
        // 2*(z.c) = acc * 2^-19 exactly; same rounding structure as fp32 kernel
        const float dist =
            __fadd_rn(__fsub_rn(Ab, __fmul_rn(av, 0x1p-19f)), qs[k]);
        const unsigned long long cand =
            ((unsigned long long)__float_as_uint(dist) << 32) | (unsigned)k;
        if (cand < b1) { b2 = b1; b1 = cand; }
        else if (cand < b2) { b2 = cand; }
      }
    }
    {
      const unsigned long long o1 = __shfl_xor(b1, 32, 64);
      const unsigned long long o2 = __shfl_xor(b2, 32, 64);
      const unsigned long long lo = (b1 < o1) ? b1 : o1;
      const unsigned long long hi = (b1 < o1) ? o1 : b1;
      const unsigned long long s2 = (b2 < o2) ? b2 : o2;
      b1 = lo;
      b2 = (hi < s2) ? hi : s2;
    }
    if (lane < 32) {
      // transposed [slot][row]: writes 2-way (free), merge reads conflict-free
      mrg[(w * 2) * BC + lr] = b1;
      mrg[(w * 2 + 1) * BC + lr] = b2;
    }
    __syncthreads();  // B2: compute/argmin done, mrg complete

    // ---- merge + (rare) exact rescore -> tok_all (LDS only; no global) ----
    if ((tid & 15) == 0) {
      const int row = tid >> 4;  // 0..31, spread across all 8 waves
      unsigned long long m1 = ~0ULL, m2 = ~0ULL;
#pragma unroll
      for (int g = 0; g < 2 * NW; ++g) {
        const unsigned long long v = mrg[g * BC + row];
        if (v < m1) { m2 = m1; m1 = v; }
        else if (v < m2) { m2 = v; }
      }
      int tok = (int)(m1 & 0xffffffffULL);
      const float d1f = __uint_as_float((unsigned)(m1 >> 32));
      const float d2f = __uint_as_float((unsigned)(m2 >> 32));
      if (d2f - d1f < TAU) {
        // near-tie: rescore both candidates with the original kernel's exact
        // fp32 fma-chain (bit-identical decisions to the passing fp32 kernel)
        const int k1 = (int)(m1 & 0xffffffffULL);
        const int k2 = (int)(m2 & 0xffffffffULL);
        const float* zp = z_e + ((size_t)(b0 + row) * TT + t) * DD;
        const float Az = As_all[bc * BC + row];
        const float e1 = dot128_chain(zp, cb + ((size_t)t * KK + k1) * DD);
        const float e2 = dot128_chain(zp, cb + ((size_t)t * KK + k2) * DD);
        const float dd1 = __fadd_rn(__fsub_rn(Az, __fmul_rn(2.0f, e1)), qs[k1]);
        const float dd2 = __fadd_rn(__fsub_rn(Az, __fmul_rn(2.0f, e2)), qs[k2]);
        const unsigned long long c1 =
            ((unsigned long long)__float_as_uint(dd1) << 32) | (unsigned)k1;
        const unsigned long long c2 =
            ((unsigned long long)__float_as_uint(dd2) << 32) | (unsigned)k2;
        tok = (int)(((c1 < c2) ? c1 : c2) & 0xffffffffULL);
      }
      tok_all[bc * BC + row] = tok;
    }
    // next loop-top stage writes zs only after B2 (prior reads done); merge
    // reads of mrg complete before this thread reaches next B1 -> race-free
  }
  __syncthreads();  // tok_all complete

  // ---- deferred epilogue: tokens + used bitmap + z_q_st + loss ----
  {
    const int tok = tok_all[tid];
    out[(size_t)N0 + (size_t)(bbase + tid) * TT + t] = (float)tok;
    atomicOr(&used[t * KK + tok], 1);
  }
  float lsum = 0.0f;
#pragma unroll
  for (int it = 0; it < 16; ++it) {
    const int idx = tid + it * 512;
    const int row = idx >> 4, unit = idx & 15;
    const int k = tok_all[row];
    const float* zp = z_e + ((size_t)(bbase + row) * TT + t) * DD + unit * 8;
    const float* cp = cb + ((size_t)t * KK + k) * DD + unit * 8;
    float* op = out + ((size_t)(bbase + row) * TT + t) * DD + unit * 8;
#pragma unroll
    for (int h = 0; h < 2; ++h) {
      const float4 zv = *(const float4*)(zp + h * 4);
      const float4 cv = *(const float4*)(cp + h * 4);
      float4 o;
      o.x = __fadd_rn(zv.x, __fsub_rn(cv.x, zv.x));
      o.y = __fadd_rn(zv.y, __fsub_rn(cv.y, zv.y));
      o.z = __fadd_rn(zv.z, __fsub_rn(cv.z, zv.z));
      o.w = __fadd_rn(zv.w, __fsub_rn(cv.w, zv.w));
      *(float4*)(op + h * 4) = o;
      const float dx = zv.x - cv.x, dy = zv.y - cv.y;
      const float dz = zv.z - cv.z, dw = zv.w - cv.w;
      lsum += dx * dx + dy * dy + dz * dz + dw * dw;
    }
  }

  // ---- block loss reduction ----
#pragma unroll
  for (int off = 32; off > 0; off >>= 1) lsum += __shfl_down(lsum, off, 64);
  if (lane == 0) wred[w] = lsum;
  __syncthreads();
  if (tid == 0) {
    float s = 0.0f;
#pragma unroll
    for (int i = 0; i < NW; ++i) s += wred[i];
    loss_part[blockIdx.y * 16 + blockIdx.x] = s;
  }
}

__global__ void vq_final(const float* __restrict__ loss_part,
                         const int* __restrict__ used, float* __restrict__ out) {
  __shared__ float partf[4];
  __shared__ int   parti[4];
  int tid = threadIdx.x;
  float ls = 0.0f;
  for (int i = tid; i < 256; i += 256) ls += loss_part[i];
  int c = 0;
  for (int i = tid; i < TT * KK; i += 256) c += used[i];
#pragma unroll
  for (int off = 32; off > 0; off >>= 1) {
    ls += __shfl_down(ls, off, 64);
    c  += __shfl_down(c, off, 64);
  }
  if ((tid & 63) == 0) { partf[tid >> 6] = ls; parti[tid >> 6] = c; }
  __syncthreads();
  if (tid == 0) {
    float lt = partf[0] + partf[1] + partf[2] + partf[3];
    int   tot = parti[0] + parti[1] + parti[2] + parti[3];
    out[(size_t)N0 + N1]     = 0.25f * lt / 16777216.0f;  // BETA * mean
    out[(size_t)N0 + N1 + 1] = (float)tot / 8192.0f;      // utilization
  }
}

extern "C" void kernel_launch(void* const* d_in, const int* in_sizes, int n_in,
                              void* d_out, int out_size, void* d_ws, size_t ws_size,
                              hipStream_t stream) {
  const float* z_e = (const float*)d_in[0];
  const float* cb  = (const float*)d_in[1];
  float* out = (float*)d_out;
  float* loss_part = (float*)d_ws;                     // 256 floats
  int*   used      = (int*)((char*)d_ws + 4096);       // 8192 ints
  hipMemsetAsync(d_ws, 0, 4096 + TT * KK * sizeof(int), stream);
  vq_main<<<dim3(8192 / BSTRIPE, TT), 512, 0, stream>>>(z_e, cb, out, loss_part, used);
  vq_final<<<1, 256, 0, stream>>>(loss_part, used, out);
}